// Round 5
// baseline (82.167 us; speedup 1.0000x reference)
//
#include <hip/hip_runtime.h>
#include <math.h>

// Dims
#define D 2048
#define NH 8
#define NKV 2
#define HD 256
#define DFF 8192
#define W 512
#define PLD 256
#define EPS 1e-6f

typedef float f32x4 __attribute__((ext_vector_type(4)));

__device__ __forceinline__ f32x4 ntld(const float* p) {
    return __builtin_nontemporal_load(reinterpret_cast<const f32x4*>(p));
}
__device__ __forceinline__ f32x4 ld4(const float* p) {
    return *reinterpret_cast<const f32x4*>(p);
}
__device__ __forceinline__ float dot4(f32x4 a, f32x4 b, float acc) {
    return fmaf(a.x, b.x, fmaf(a.y, b.y, fmaf(a.z, b.z, fmaf(a.w, b.w, acc))));
}

// butterfly reductions: ALL 64 lanes end with the full result
__device__ __forceinline__ float wave_sum(float v) {
    #pragma unroll
    for (int off = 32; off > 0; off >>= 1) v += __shfl_xor(v, off, 64);
    return v;
}
__device__ __forceinline__ float wave_max(float v) {
    #pragma unroll
    for (int off = 32; off > 0; off >>= 1) v = fmaxf(v, __shfl_xor(v, off, 64));
    return v;
}

__device__ __forceinline__ float gelu_tanh(float x) {
    const float c = 0.7978845608028654f; // sqrt(2/pi)
    float t = tanhf(c * (x + 0.044715f * x * x * x));
    return 0.5f * x * (1.0f + t);
}

// =====================================================================
// 1) qkv_fused: input rmsnorm per-wave (butterfly), then GEMV. 768x256.
// =====================================================================
__global__ __launch_bounds__(256, 1)
void qkv_fused(const float* __restrict__ Wq, const float* __restrict__ Wk,
               const float* __restrict__ Wv, const float* __restrict__ x,
               const float* __restrict__ lnw, float* __restrict__ qraw,
               float* __restrict__ kraw, float* __restrict__ vraw) {
    int lane = threadIdx.x & 63, wid = threadIdx.x >> 6;
    int row = blockIdx.x * 4 + wid; // 0..3071
    const float* wr;
    float* outp;
    if (row < 2048)      { wr = Wq + (size_t)row * D;          outp = qraw + row; }
    else if (row < 2560) { wr = Wk + (size_t)(row - 2048) * D; outp = kraw + (row - 2048); }
    else                 { wr = Wv + (size_t)(row - 2560) * D; outp = vraw + (row - 2560); }
    f32x4 xv[8], lw[8];
    #pragma unroll
    for (int c = 0; c < 8; c++) xv[c] = ld4(x + c * 256 + lane * 4);
    #pragma unroll
    for (int c = 0; c < 8; c++) lw[c] = ld4(lnw + c * 256 + lane * 4);
    f32x4 wv4[8];
    #pragma unroll
    for (int c = 0; c < 8; c++) wv4[c] = ntld(wr + c * 256 + lane * 4);
    float ss = 0.f;
    #pragma unroll
    for (int c = 0; c < 8; c++) ss = dot4(xv[c], xv[c], ss);
    ss = wave_sum(ss);
    float rs = rsqrtf(ss / (float)D + EPS);
    float acc = 0.f;
    #pragma unroll
    for (int c = 0; c < 8; c++) {
        f32x4 h4 = xv[c] * rs * (1.f + lw[c]);
        acc = dot4(wv4[c], h4, acc);
    }
    acc = wave_sum(acc);
    if (lane == 0) *outp = acc;
}

// =====================================================================
// 2) attn_fused: per-head block (8 x 1024). norms + RoPE + scores +
//    softmax + PV in one kernel.
// =====================================================================
__global__ __launch_bounds__(1024, 1)
void attn_fused(const float* __restrict__ kvc, const float* __restrict__ qraw,
                const float* __restrict__ kraw, const float* __restrict__ vraw,
                const float* __restrict__ qw, const float* __restrict__ kw,
                const float* __restrict__ cosv, const float* __restrict__ sinv,
                const float* __restrict__ mask, const int* __restrict__ ring_p,
                float* __restrict__ attn_o) {
    __shared__ float qn[HD], kn[HD], vn[HD], p[W], red[16], oacc[4][HD];
    int t = threadIdx.x, wv = t >> 6, lane = t & 63;
    int head = blockIdx.x, kvh = head >> 2;
    int ring = *ring_p;
    if (wv == 0) { // q head: rmsnorm + rope
        f32x4 v4 = ld4(qraw + head * HD + lane * 4);
        float ss = wave_sum(dot4(v4, v4, 0.f));
        float rs = rsqrtf(ss / (float)HD + EPS);
        f32x4 w4 = ld4(qw + lane * 4);
        f32x4 nv = v4 * rs * (1.f + w4);
        f32x4 pr;
        pr.x = __shfl_xor(nv.x, 32, 64);
        pr.y = __shfl_xor(nv.y, 32, 64);
        pr.z = __shfl_xor(nv.z, 32, 64);
        pr.w = __shfl_xor(nv.w, 32, 64);
        f32x4 c4 = ld4(cosv + lane * 4), s4 = ld4(sinv + lane * 4);
        float sgn = (lane < 32) ? -1.f : 1.f;
        f32x4 o4 = nv * c4 + pr * s4 * sgn;
        *reinterpret_cast<f32x4*>(qn + lane * 4) = o4;
    } else if (wv == 1) { // k head: rmsnorm + rope
        f32x4 v4 = ld4(kraw + kvh * HD + lane * 4);
        float ss = wave_sum(dot4(v4, v4, 0.f));
        float rs = rsqrtf(ss / (float)HD + EPS);
        f32x4 w4 = ld4(kw + lane * 4);
        f32x4 nv = v4 * rs * (1.f + w4);
        f32x4 pr;
        pr.x = __shfl_xor(nv.x, 32, 64);
        pr.y = __shfl_xor(nv.y, 32, 64);
        pr.z = __shfl_xor(nv.z, 32, 64);
        pr.w = __shfl_xor(nv.w, 32, 64);
        f32x4 c4 = ld4(cosv + lane * 4), s4 = ld4(sinv + lane * 4);
        float sgn = (lane < 32) ? -1.f : 1.f;
        f32x4 o4 = nv * c4 + pr * s4 * sgn;
        *reinterpret_cast<f32x4*>(kn + lane * 4) = o4;
    } else if (wv == 2) { // v head: weightless rmsnorm
        f32x4 v4 = ld4(vraw + kvh * HD + lane * 4);
        float ss = wave_sum(dot4(v4, v4, 0.f));
        float rs = rsqrtf(ss / (float)HD + EPS);
        *reinterpret_cast<f32x4*>(vn + lane * 4) = v4 * rs;
    }
    __syncthreads();
    // scores: 16 waves x 32 positions
    {
        f32x4 qq = *reinterpret_cast<f32x4*>(qn + lane * 4);
        f32x4 krg = *reinterpret_cast<f32x4*>(kn + lane * 4);
        const float* Kb = kvc + (size_t)kvh * W * HD;
        #pragma unroll 4
        for (int i = 0; i < 32; i++) {
            int w = wv * 32 + i;
            f32x4 k4 = (w == ring) ? krg : ld4(Kb + (size_t)w * HD + lane * 4);
            float s = wave_sum(dot4(qq, k4, 0.f));
            if (lane == 0) p[w] = s + mask[w];
        }
    }
    __syncthreads();
    // softmax over 512 (first 8 waves own one element each)
    float e = 0.f, sv = 0.f;
    if (t < W) {
        sv = p[t];
        float m = wave_max(sv);
        if (lane == 0) red[wv] = m;
    }
    __syncthreads();
    float m = red[0];
    #pragma unroll
    for (int i = 1; i < 8; i++) m = fmaxf(m, red[i]);
    if (t < W) e = expf(sv - m);
    __syncthreads();
    if (t < W) {
        float se = wave_sum(e);
        if (lane == 0) red[wv] = se;
    }
    __syncthreads();
    float tot = 0.f;
    #pragma unroll
    for (int i = 0; i < 8; i++) tot += red[i];
    if (t < W) p[t] = e / tot;
    __syncthreads();
    // PV: quarter of positions each, thread owns d
    {
        int d = t & 255, q = t >> 8;
        float vr = vn[d];
        const float* Vb = kvc + (size_t)(NKV + kvh) * W * HD;
        float acc = 0.f;
        #pragma unroll 8
        for (int i = 0; i < 128; i++) {
            int w = q * 128 + i;
            float vv = (w == ring) ? vr : Vb[(size_t)w * HD + d];
            acc = fmaf(p[w], vv, acc);
        }
        oacc[q][d] = acc;
    }
    __syncthreads();
    if (t < HD) attn_o[head * HD + t] = oacc[0][t] + oacc[1][t] + oacc[2][t] + oacc[3][t];
}

// =====================================================================
// 3) plain 2048-col GEMV (Wo)
// =====================================================================
__global__ __launch_bounds__(256, 1)
void gemv2048_nt(const float* __restrict__ Wm, const float* __restrict__ x,
                 float* __restrict__ y) {
    int lane = threadIdx.x & 63, wid = threadIdx.x >> 6;
    int row = blockIdx.x * 4 + wid;
    const float* wr = Wm + (size_t)row * D;
    f32x4 xv[8], w[8];
    #pragma unroll
    for (int c = 0; c < 8; c++) xv[c] = ld4(x + c * 256 + lane * 4);
    #pragma unroll
    for (int c = 0; c < 8; c++) w[c] = ntld(wr + c * 256 + lane * 4);
    float acc = 0.f;
    #pragma unroll
    for (int c = 0; c < 8; c++) acc = dot4(w[c], xv[c], acc);
    acc = wave_sum(acc);
    if (lane == 0) y[row] = acc;
}

// =====================================================================
// 4) gateup_fused: residual+2 rmsnorms per-wave, then dual GEMV. 2048x256.
// =====================================================================
__global__ __launch_bounds__(256, 1)
void gateup_fused(const float* __restrict__ Wg, const float* __restrict__ Wu,
                  const float* __restrict__ x, const float* __restrict__ ywo,
                  const float* __restrict__ w_pa, const float* __restrict__ w_pf,
                  float* __restrict__ act, float* __restrict__ x1out) {
    int lane = threadIdx.x & 63, wid = threadIdx.x >> 6;
    int row = blockIdx.x * 4 + wid; // 0..8191
    const float* wg = Wg + (size_t)row * D;
    const float* wu = Wu + (size_t)row * D;
    f32x4 y4[8], xr4[8], w1[8], w2[8];
    #pragma unroll
    for (int c = 0; c < 8; c++) y4[c] = ld4(ywo + c * 256 + lane * 4);
    #pragma unroll
    for (int c = 0; c < 8; c++) xr4[c] = ld4(x + c * 256 + lane * 4);
    #pragma unroll
    for (int c = 0; c < 8; c++) w1[c] = ld4(w_pa + c * 256 + lane * 4);
    #pragma unroll
    for (int c = 0; c < 8; c++) w2[c] = ld4(w_pf + c * 256 + lane * 4);
    f32x4 g4[8], u4[8];
    #pragma unroll
    for (int c = 0; c < 8; c++) g4[c] = ntld(wg + c * 256 + lane * 4);
    #pragma unroll
    for (int c = 0; c < 8; c++) u4[c] = ntld(wu + c * 256 + lane * 4);
    float ss = 0.f;
    #pragma unroll
    for (int c = 0; c < 8; c++) ss = dot4(y4[c], y4[c], ss);
    ss = wave_sum(ss);
    float rs1 = rsqrtf(ss / (float)D + EPS);
    f32x4 x1v[8];
    float s2 = 0.f;
    #pragma unroll
    for (int c = 0; c < 8; c++) {
        f32x4 v = xr4[c] + y4[c] * rs1 * (1.f + w1[c]);
        x1v[c] = v;
        s2 = dot4(v, v, s2);
    }
    s2 = wave_sum(s2);
    float rs2 = rsqrtf(s2 / (float)D + EPS);
    if (blockIdx.x == 0 && wid == 0) {
        #pragma unroll
        for (int c = 0; c < 8; c++)
            *reinterpret_cast<f32x4*>(x1out + c * 256 + lane * 4) = x1v[c];
    }
    float ag = 0.f, au = 0.f;
    #pragma unroll
    for (int c = 0; c < 8; c++) {
        f32x4 h4 = x1v[c] * rs2 * (1.f + w2[c]);
        ag = dot4(g4[c], h4, ag);
        au = dot4(u4[c], h4, au);
    }
    ag = wave_sum(ag);
    au = wave_sum(au);
    if (lane == 0) act[row] = gelu_tanh(ag) * au;
}

// =====================================================================
// 5) Wdown GEMV (2048 rows x 8192), ping-pong register sections, NT
// =====================================================================
__global__ __launch_bounds__(256, 1)
void down_nt(const float* __restrict__ Wd, const float* __restrict__ act,
             float* __restrict__ y) {
    int lane = threadIdx.x & 63, wid = threadIdx.x >> 6;
    int row = blockIdx.x * 4 + wid; // 0..2047
    const float* wr = Wd + (size_t)row * DFF;
    f32x4 wA[8], wB[8], a[8];
    float acc = 0.f;
    #pragma unroll
    for (int c = 0; c < 8; c++) a[c] = ld4(act + c * 256 + lane * 4);
    #pragma unroll
    for (int c = 0; c < 8; c++) wA[c] = ntld(wr + c * 256 + lane * 4);
    #pragma unroll
    for (int c = 0; c < 8; c++) wB[c] = ntld(wr + 2048 + c * 256 + lane * 4);
    #pragma unroll
    for (int c = 0; c < 8; c++) acc = dot4(wA[c], a[c], acc);
    #pragma unroll
    for (int c = 0; c < 8; c++) a[c] = ld4(act + 2048 + c * 256 + lane * 4);
    #pragma unroll
    for (int c = 0; c < 8; c++) wA[c] = ntld(wr + 4096 + c * 256 + lane * 4);
    #pragma unroll
    for (int c = 0; c < 8; c++) acc = dot4(wB[c], a[c], acc);
    #pragma unroll
    for (int c = 0; c < 8; c++) a[c] = ld4(act + 4096 + c * 256 + lane * 4);
    #pragma unroll
    for (int c = 0; c < 8; c++) wB[c] = ntld(wr + 6144 + c * 256 + lane * 4);
    #pragma unroll
    for (int c = 0; c < 8; c++) acc = dot4(wA[c], a[c], acc);
    #pragma unroll
    for (int c = 0; c < 8; c++) a[c] = ld4(act + 6144 + c * 256 + lane * 4);
    #pragma unroll
    for (int c = 0; c < 8; c++) acc = dot4(wB[c], a[c], acc);
    acc = wave_sum(acc);
    if (lane == 0) y[row] = acc;
}

// =====================================================================
// 6) plgate_fused: x2 = x1 + rmsnorm(y2)*(1+w_pf) per-wave, then
//    g[row] = gelu(Wpl_gate[row].x2) * per_layer[row]. 64x256.
// =====================================================================
__global__ __launch_bounds__(256, 1)
void plgate_fused(const float* __restrict__ Wpl, const float* __restrict__ x1,
                  const float* __restrict__ y2, const float* __restrict__ w_pf,
                  const float* __restrict__ per_layer, float* __restrict__ g,
                  float* __restrict__ x2out) {
    int lane = threadIdx.x & 63, wid = threadIdx.x >> 6;
    int row = blockIdx.x * 4 + wid; // 0..255
    f32x4 y4[8], x4[8], w4[8];
    #pragma unroll
    for (int c = 0; c < 8; c++) y4[c] = ld4(y2 + c * 256 + lane * 4);
    #pragma unroll
    for (int c = 0; c < 8; c++) x4[c] = ld4(x1 + c * 256 + lane * 4);
    #pragma unroll
    for (int c = 0; c < 8; c++) w4[c] = ld4(w_pf + c * 256 + lane * 4);
    f32x4 wv4[8];
    const float* wr = Wpl + (size_t)row * D;
    #pragma unroll
    for (int c = 0; c < 8; c++) wv4[c] = ntld(wr + c * 256 + lane * 4);
    float ss = 0.f;
    #pragma unroll
    for (int c = 0; c < 8; c++) ss = dot4(y4[c], y4[c], ss);
    ss = wave_sum(ss);
    float rs = rsqrtf(ss / (float)D + EPS);
    f32x4 x2v[8];
    #pragma unroll
    for (int c = 0; c < 8; c++) x2v[c] = x4[c] + y4[c] * rs * (1.f + w4[c]);
    if (blockIdx.x == 0 && wid == 0) {
        #pragma unroll
        for (int c = 0; c < 8; c++)
            *reinterpret_cast<f32x4*>(x2out + c * 256 + lane * 4) = x2v[c];
    }
    float acc = 0.f;
    #pragma unroll
    for (int c = 0; c < 8; c++) acc = dot4(wv4[c], x2v[c], acc);
    acc = wave_sum(acc);
    if (lane == 0) g[row] = gelu_tanh(acc) * per_layer[row];
}

// =====================================================================
// 7) tiny 256-col GEMV (Wpl_proj): 512x256
// =====================================================================
__global__ __launch_bounds__(256, 1)
void gemv256_nt(const float* __restrict__ Wm, const float* __restrict__ x,
                float* __restrict__ y) {
    int lane = threadIdx.x & 63, wid = threadIdx.x >> 6;
    int row = blockIdx.x * 4 + wid;
    f32x4 x0 = ld4(x + lane * 4);
    f32x4 w0 = ntld(Wm + (size_t)row * PLD + lane * 4);
    float acc = dot4(w0, x0, 0.f);
    acc = wave_sum(acc);
    if (lane == 0) y[row] = acc;
}

// =====================================================================
// 8) final_fused: out = (x2 + rmsnorm(g2)*(1+w)) * scal. 8x256.
// =====================================================================
__global__ __launch_bounds__(256, 1)
void final_fused(const float* __restrict__ x2, const float* __restrict__ g2,
                 const float* __restrict__ w, const float* __restrict__ scal,
                 float* __restrict__ out) {
    int lane = threadIdx.x & 63;
    f32x4 g4[8];
    #pragma unroll
    for (int c = 0; c < 8; c++) g4[c] = ld4(g2 + c * 256 + lane * 4);
    float ss = 0.f;
    #pragma unroll
    for (int c = 0; c < 8; c++) ss = dot4(g4[c], g4[c], ss);
    ss = wave_sum(ss);
    float rs = rsqrtf(ss / (float)D + EPS);
    int idx = blockIdx.x * 256 + threadIdx.x;
    out[idx] = (x2[idx] + g2[idx] * rs * (1.f + w[idx])) * scal[0];
}

extern "C" void kernel_launch(void* const* d_in, const int* in_sizes, int n_in,
                              void* d_out, int out_size, void* d_ws, size_t ws_size,
                              hipStream_t stream) {
    const float* x_in        = (const float*)d_in[0];
    const float* cosv        = (const float*)d_in[1];
    const float* sinv        = (const float*)d_in[2];
    const float* mask        = (const float*)d_in[3];
    const float* kvc         = (const float*)d_in[4];
    const float* per_layer   = (const float*)d_in[5];
    const float* ln_in_w     = (const float*)d_in[6];
    const float* Wq          = (const float*)d_in[7];
    const float* q_norm_w    = (const float*)d_in[8];
    const float* Wk          = (const float*)d_in[9];
    const float* Wv          = (const float*)d_in[10];
    const float* k_norm_w    = (const float*)d_in[11];
    const float* Wo          = (const float*)d_in[12];
    const float* post_attn_w = (const float*)d_in[13];
    const float* pre_ffn_w   = (const float*)d_in[14];
    const float* Wgate       = (const float*)d_in[15];
    const float* Wup         = (const float*)d_in[16];
    const float* Wdown       = (const float*)d_in[17];
    const float* post_ffn_w  = (const float*)d_in[18];
    const float* Wpl_gate    = (const float*)d_in[19];
    const float* Wpl_proj    = (const float*)d_in[20];
    const float* post_pl_w   = (const float*)d_in[21];
    const float* layer_scal  = (const float*)d_in[22];
    const int*   ring_pos    = (const int*)d_in[23];
    float* out = (float*)d_out;
    float* ws  = (float*)d_ws;

    float* qraw   = ws;          // 2048
    float* kraw   = ws + 2048;   // 512
    float* vraw   = ws + 2560;   // 512
    float* attn_o = ws + 3072;   // 2048
    float* y_wo   = ws + 5120;   // 2048
    float* x1     = ws + 7168;   // 2048
    float* act    = ws + 9216;   // 8192
    float* y2     = ws + 17408;  // 2048
    float* x2     = ws + 19456;  // 2048
    float* g      = ws + 21504;  // 256
    float* g2     = ws + 21760;  // 2048

    qkv_fused<<<768, 256, 0, stream>>>(Wq, Wk, Wv, x_in, ln_in_w, qraw, kraw, vraw);
    attn_fused<<<8, 1024, 0, stream>>>(kvc, qraw, kraw, vraw, q_norm_w, k_norm_w,
                                       cosv, sinv, mask, ring_pos, attn_o);
    gemv2048_nt<<<512, 256, 0, stream>>>(Wo, attn_o, y_wo);
    gateup_fused<<<2048, 256, 0, stream>>>(Wgate, Wup, x_in, y_wo,
                                           post_attn_w, pre_ffn_w, act, x1);
    down_nt<<<512, 256, 0, stream>>>(Wdown, act, y2);
    plgate_fused<<<64, 256, 0, stream>>>(Wpl_gate, x1, y2, post_ffn_w,
                                         per_layer, g, x2);
    gemv256_nt<<<512, 256, 0, stream>>>(Wpl_proj, g, g2);
    final_fused<<<8, 256, 0, stream>>>(x2, g2, post_pl_w, layer_scal, out);
}

// Round 6
// 74.706 us; speedup vs baseline: 1.0999x; 1.0999x over previous
//
#include <hip/hip_runtime.h>
#include <math.h>

// Dims
#define D 2048
#define NH 8
#define NKV 2
#define HD 256
#define DFF 8192
#define W 512
#define PLD 256
#define EPS 1e-6f

typedef float f32x4 __attribute__((ext_vector_type(4)));

__device__ __forceinline__ f32x4 ntld(const float* p) {
    return __builtin_nontemporal_load(reinterpret_cast<const f32x4*>(p));
}
__device__ __forceinline__ f32x4 ld4(const float* p) {
    return *reinterpret_cast<const f32x4*>(p);
}
__device__ __forceinline__ float dot4(f32x4 a, f32x4 b, float acc) {
    return fmaf(a.x, b.x, fmaf(a.y, b.y, fmaf(a.z, b.z, fmaf(a.w, b.w, acc))));
}

// butterfly reductions: ALL 64 lanes end with the full result
__device__ __forceinline__ float wave_sum(float v) {
    #pragma unroll
    for (int off = 32; off > 0; off >>= 1) v += __shfl_xor(v, off, 64);
    return v;
}
__device__ __forceinline__ float wave_max(float v) {
    #pragma unroll
    for (int off = 32; off > 0; off >>= 1) v = fmaxf(v, __shfl_xor(v, off, 64));
    return v;
}

__device__ __forceinline__ float gelu_tanh(float x) {
    const float c = 0.7978845608028654f; // sqrt(2/pi)
    float t = tanhf(c * (x + 0.044715f * x * x * x));
    return 0.5f * x * (1.0f + t);
}

// =====================================================================
// 1) qkv_fused: input rmsnorm per-wave (butterfly), then GEMV. 768x256.
// =====================================================================
__global__ __launch_bounds__(256, 1)
void qkv_fused(const float* __restrict__ Wq, const float* __restrict__ Wk,
               const float* __restrict__ Wv, const float* __restrict__ x,
               const float* __restrict__ lnw, float* __restrict__ qraw,
               float* __restrict__ kraw, float* __restrict__ vraw) {
    int lane = threadIdx.x & 63, wid = threadIdx.x >> 6;
    int row = blockIdx.x * 4 + wid; // 0..3071
    const float* wr;
    float* outp;
    if (row < 2048)      { wr = Wq + (size_t)row * D;          outp = qraw + row; }
    else if (row < 2560) { wr = Wk + (size_t)(row - 2048) * D; outp = kraw + (row - 2048); }
    else                 { wr = Wv + (size_t)(row - 2560) * D; outp = vraw + (row - 2560); }
    f32x4 xv[8], lw[8];
    #pragma unroll
    for (int c = 0; c < 8; c++) xv[c] = ld4(x + c * 256 + lane * 4);
    #pragma unroll
    for (int c = 0; c < 8; c++) lw[c] = ld4(lnw + c * 256 + lane * 4);
    f32x4 wv4[8];
    #pragma unroll
    for (int c = 0; c < 8; c++) wv4[c] = ntld(wr + c * 256 + lane * 4);
    float ss = 0.f;
    #pragma unroll
    for (int c = 0; c < 8; c++) ss = dot4(xv[c], xv[c], ss);
    ss = wave_sum(ss);
    float rs = rsqrtf(ss / (float)D + EPS);
    float acc = 0.f;
    #pragma unroll
    for (int c = 0; c < 8; c++) {
        f32x4 h4 = xv[c] * rs * (1.f + lw[c]);
        acc = dot4(wv4[c], h4, acc);
    }
    acc = wave_sum(acc);
    if (lane == 0) *outp = acc;
}

// =====================================================================
// 2) attn_scores_f: 64 blocks (head*8+chunk) x 256. Wave 0/1 compute
//    qn/kn (rmsnorm+RoPE, verified R5 code) into LDS; 4 waves x 16 scores.
// =====================================================================
__global__ __launch_bounds__(256, 1)
void attn_scores_f(const float* __restrict__ kvc, const float* __restrict__ qraw,
                   const float* __restrict__ kraw, const float* __restrict__ qw,
                   const float* __restrict__ kw, const float* __restrict__ cosv,
                   const float* __restrict__ sinv, const float* __restrict__ mask,
                   const int* __restrict__ ring_p, float* __restrict__ scores) {
    __shared__ float qn[HD], kn[HD];
    int t = threadIdx.x, wv = t >> 6, lane = t & 63;
    int head = blockIdx.x >> 3, wc = blockIdx.x & 7, kvh = head >> 2;
    int ring = *ring_p;
    if (wv == 0) { // q head: rmsnorm + rope
        f32x4 v4 = ld4(qraw + head * HD + lane * 4);
        float ss = wave_sum(dot4(v4, v4, 0.f));
        float rs = rsqrtf(ss / (float)HD + EPS);
        f32x4 w4 = ld4(qw + lane * 4);
        f32x4 nv = v4 * rs * (1.f + w4);
        f32x4 pr;
        pr.x = __shfl_xor(nv.x, 32, 64);
        pr.y = __shfl_xor(nv.y, 32, 64);
        pr.z = __shfl_xor(nv.z, 32, 64);
        pr.w = __shfl_xor(nv.w, 32, 64);
        f32x4 c4 = ld4(cosv + lane * 4), s4 = ld4(sinv + lane * 4);
        float sgn = (lane < 32) ? -1.f : 1.f;
        *reinterpret_cast<f32x4*>(qn + lane * 4) = nv * c4 + pr * s4 * sgn;
    } else if (wv == 1) { // k head: rmsnorm + rope
        f32x4 v4 = ld4(kraw + kvh * HD + lane * 4);
        float ss = wave_sum(dot4(v4, v4, 0.f));
        float rs = rsqrtf(ss / (float)HD + EPS);
        f32x4 w4 = ld4(kw + lane * 4);
        f32x4 nv = v4 * rs * (1.f + w4);
        f32x4 pr;
        pr.x = __shfl_xor(nv.x, 32, 64);
        pr.y = __shfl_xor(nv.y, 32, 64);
        pr.z = __shfl_xor(nv.z, 32, 64);
        pr.w = __shfl_xor(nv.w, 32, 64);
        f32x4 c4 = ld4(cosv + lane * 4), s4 = ld4(sinv + lane * 4);
        float sgn = (lane < 32) ? -1.f : 1.f;
        *reinterpret_cast<f32x4*>(kn + lane * 4) = nv * c4 + pr * s4 * sgn;
    }
    __syncthreads();
    f32x4 qq = *reinterpret_cast<f32x4*>(qn + lane * 4);
    f32x4 krg = *reinterpret_cast<f32x4*>(kn + lane * 4);
    const float* Kb = kvc + (size_t)kvh * W * HD;
    #pragma unroll 4
    for (int i = 0; i < 16; i++) {
        int w = wc * 64 + wv * 16 + i;
        f32x4 k4 = (w == ring) ? krg : ld4(Kb + (size_t)w * HD + lane * 4);
        float s = wave_sum(dot4(qq, k4, 0.f));
        if (lane == 0) scores[head * W + w] = s + mask[w];
    }
}

// =====================================================================
// 3) attn_softmax: 8 blocks x 256, butterfly + LDS cross-wave; zeroes attn_o
// =====================================================================
__global__ __launch_bounds__(256, 1)
void attn_softmax(float* __restrict__ scores, float* __restrict__ attn_o) {
    __shared__ float s4[4];
    int head = blockIdx.x, t = threadIdx.x, lane = t & 63, wv = t >> 6;
    float s0 = scores[head * W + t], s1 = scores[head * W + 256 + t];
    float m = wave_max(fmaxf(s0, s1));
    if (lane == 0) s4[wv] = m;
    __syncthreads();
    m = fmaxf(fmaxf(s4[0], s4[1]), fmaxf(s4[2], s4[3]));
    __syncthreads();
    float e0 = expf(s0 - m), e1 = expf(s1 - m);
    float se = wave_sum(e0 + e1);
    if (lane == 0) s4[wv] = se;
    __syncthreads();
    float tot = s4[0] + s4[1] + s4[2] + s4[3];
    float inv = 1.f / tot;
    scores[head * W + t] = e0 * inv;
    scores[head * W + 256 + t] = e1 * inv;
    attn_o[head * HD + t] = 0.f;
}

// =====================================================================
// 4) attn_pv: 64 blocks (head*8+chunk) x 256, thread owns d, atomicAdd.
//    v weightless rmsnorm computed per-wave redundantly.
// =====================================================================
__global__ __launch_bounds__(256, 1)
void attn_pv(const float* __restrict__ kvc, const float* __restrict__ vraw,
             const float* __restrict__ p, const int* __restrict__ ring_p,
             float* __restrict__ attn_o) {
    int t = threadIdx.x, lane = t & 63;
    int head = blockIdx.x >> 3, wc = blockIdx.x & 7, kvh = head >> 2;
    int ring = *ring_p;
    f32x4 v4 = ld4(vraw + kvh * HD + lane * 4);
    float ss = wave_sum(dot4(v4, v4, 0.f));
    float rs = rsqrtf(ss / (float)HD + EPS);
    float vr = vraw[kvh * HD + t] * rs;
    const float* Vb = kvc + (size_t)(NKV + kvh) * W * HD;
    float acc = 0.f;
    #pragma unroll 8
    for (int i = 0; i < 64; i++) {
        int w = wc * 64 + i;
        float vv = (w == ring) ? vr : Vb[(size_t)w * HD + t];
        acc = fmaf(p[head * W + w], vv, acc);
    }
    atomicAdd(&attn_o[head * HD + t], acc);
}

// =====================================================================
// 5) plain 2048-col GEMV (Wo)
// =====================================================================
__global__ __launch_bounds__(256, 1)
void gemv2048_nt(const float* __restrict__ Wm, const float* __restrict__ x,
                 float* __restrict__ y) {
    int lane = threadIdx.x & 63, wid = threadIdx.x >> 6;
    int row = blockIdx.x * 4 + wid;
    const float* wr = Wm + (size_t)row * D;
    f32x4 xv[8], w[8];
    #pragma unroll
    for (int c = 0; c < 8; c++) xv[c] = ld4(x + c * 256 + lane * 4);
    #pragma unroll
    for (int c = 0; c < 8; c++) w[c] = ntld(wr + c * 256 + lane * 4);
    float acc = 0.f;
    #pragma unroll
    for (int c = 0; c < 8; c++) acc = dot4(w[c], xv[c], acc);
    acc = wave_sum(acc);
    if (lane == 0) y[row] = acc;
}

// =====================================================================
// 6) gateup_fused: residual+2 rmsnorms per-wave, then dual GEMV. 2048x256.
// =====================================================================
__global__ __launch_bounds__(256, 1)
void gateup_fused(const float* __restrict__ Wg, const float* __restrict__ Wu,
                  const float* __restrict__ x, const float* __restrict__ ywo,
                  const float* __restrict__ w_pa, const float* __restrict__ w_pf,
                  float* __restrict__ act, float* __restrict__ x1out) {
    int lane = threadIdx.x & 63, wid = threadIdx.x >> 6;
    int row = blockIdx.x * 4 + wid; // 0..8191
    const float* wg = Wg + (size_t)row * D;
    const float* wu = Wu + (size_t)row * D;
    f32x4 y4[8], xr4[8], w1[8], w2[8];
    #pragma unroll
    for (int c = 0; c < 8; c++) y4[c] = ld4(ywo + c * 256 + lane * 4);
    #pragma unroll
    for (int c = 0; c < 8; c++) xr4[c] = ld4(x + c * 256 + lane * 4);
    #pragma unroll
    for (int c = 0; c < 8; c++) w1[c] = ld4(w_pa + c * 256 + lane * 4);
    #pragma unroll
    for (int c = 0; c < 8; c++) w2[c] = ld4(w_pf + c * 256 + lane * 4);
    f32x4 g4[8], u4[8];
    #pragma unroll
    for (int c = 0; c < 8; c++) g4[c] = ntld(wg + c * 256 + lane * 4);
    #pragma unroll
    for (int c = 0; c < 8; c++) u4[c] = ntld(wu + c * 256 + lane * 4);
    float ss = 0.f;
    #pragma unroll
    for (int c = 0; c < 8; c++) ss = dot4(y4[c], y4[c], ss);
    ss = wave_sum(ss);
    float rs1 = rsqrtf(ss / (float)D + EPS);
    f32x4 x1v[8];
    float s2 = 0.f;
    #pragma unroll
    for (int c = 0; c < 8; c++) {
        f32x4 v = xr4[c] + y4[c] * rs1 * (1.f + w1[c]);
        x1v[c] = v;
        s2 = dot4(v, v, s2);
    }
    s2 = wave_sum(s2);
    float rs2 = rsqrtf(s2 / (float)D + EPS);
    if (blockIdx.x == 0 && wid == 0) {
        #pragma unroll
        for (int c = 0; c < 8; c++)
            *reinterpret_cast<f32x4*>(x1out + c * 256 + lane * 4) = x1v[c];
    }
    float ag = 0.f, au = 0.f;
    #pragma unroll
    for (int c = 0; c < 8; c++) {
        f32x4 h4 = x1v[c] * rs2 * (1.f + w2[c]);
        ag = dot4(g4[c], h4, ag);
        au = dot4(u4[c], h4, au);
    }
    ag = wave_sum(ag);
    au = wave_sum(au);
    if (lane == 0) act[row] = gelu_tanh(ag) * au;
}

// =====================================================================
// 7) Wdown GEMV (2048 rows x 8192), ping-pong register sections, NT
// =====================================================================
__global__ __launch_bounds__(256, 1)
void down_nt(const float* __restrict__ Wd, const float* __restrict__ act,
             float* __restrict__ y) {
    int lane = threadIdx.x & 63, wid = threadIdx.x >> 6;
    int row = blockIdx.x * 4 + wid; // 0..2047
    const float* wr = Wd + (size_t)row * DFF;
    f32x4 wA[8], wB[8], a[8];
    float acc = 0.f;
    #pragma unroll
    for (int c = 0; c < 8; c++) a[c] = ld4(act + c * 256 + lane * 4);
    #pragma unroll
    for (int c = 0; c < 8; c++) wA[c] = ntld(wr + c * 256 + lane * 4);
    #pragma unroll
    for (int c = 0; c < 8; c++) wB[c] = ntld(wr + 2048 + c * 256 + lane * 4);
    #pragma unroll
    for (int c = 0; c < 8; c++) acc = dot4(wA[c], a[c], acc);
    #pragma unroll
    for (int c = 0; c < 8; c++) a[c] = ld4(act + 2048 + c * 256 + lane * 4);
    #pragma unroll
    for (int c = 0; c < 8; c++) wA[c] = ntld(wr + 4096 + c * 256 + lane * 4);
    #pragma unroll
    for (int c = 0; c < 8; c++) acc = dot4(wB[c], a[c], acc);
    #pragma unroll
    for (int c = 0; c < 8; c++) a[c] = ld4(act + 4096 + c * 256 + lane * 4);
    #pragma unroll
    for (int c = 0; c < 8; c++) wB[c] = ntld(wr + 6144 + c * 256 + lane * 4);
    #pragma unroll
    for (int c = 0; c < 8; c++) acc = dot4(wA[c], a[c], acc);
    #pragma unroll
    for (int c = 0; c < 8; c++) a[c] = ld4(act + 6144 + c * 256 + lane * 4);
    #pragma unroll
    for (int c = 0; c < 8; c++) acc = dot4(wB[c], a[c], acc);
    acc = wave_sum(acc);
    if (lane == 0) y[row] = acc;
}

// =====================================================================
// 8) plgate_fused: x2 = x1 + rmsnorm(y2)*(1+w_pf) per-wave, then
//    g[row] = gelu(Wpl_gate[row].x2) * per_layer[row]. 64x256.
// =====================================================================
__global__ __launch_bounds__(256, 1)
void plgate_fused(const float* __restrict__ Wpl, const float* __restrict__ x1,
                  const float* __restrict__ y2, const float* __restrict__ w_pf,
                  const float* __restrict__ per_layer, float* __restrict__ g,
                  float* __restrict__ x2out) {
    int lane = threadIdx.x & 63, wid = threadIdx.x >> 6;
    int row = blockIdx.x * 4 + wid; // 0..255
    f32x4 y4[8], x4[8], w4[8];
    #pragma unroll
    for (int c = 0; c < 8; c++) y4[c] = ld4(y2 + c * 256 + lane * 4);
    #pragma unroll
    for (int c = 0; c < 8; c++) x4[c] = ld4(x1 + c * 256 + lane * 4);
    #pragma unroll
    for (int c = 0; c < 8; c++) w4[c] = ld4(w_pf + c * 256 + lane * 4);
    f32x4 wv4[8];
    const float* wr = Wpl + (size_t)row * D;
    #pragma unroll
    for (int c = 0; c < 8; c++) wv4[c] = ntld(wr + c * 256 + lane * 4);
    float ss = 0.f;
    #pragma unroll
    for (int c = 0; c < 8; c++) ss = dot4(y4[c], y4[c], ss);
    ss = wave_sum(ss);
    float rs = rsqrtf(ss / (float)D + EPS);
    f32x4 x2v[8];
    #pragma unroll
    for (int c = 0; c < 8; c++) x2v[c] = x4[c] + y4[c] * rs * (1.f + w4[c]);
    if (blockIdx.x == 0 && wid == 0) {
        #pragma unroll
        for (int c = 0; c < 8; c++)
            *reinterpret_cast<f32x4*>(x2out + c * 256 + lane * 4) = x2v[c];
    }
    float acc = 0.f;
    #pragma unroll
    for (int c = 0; c < 8; c++) acc = dot4(wv4[c], x2v[c], acc);
    acc = wave_sum(acc);
    if (lane == 0) g[row] = gelu_tanh(acc) * per_layer[row];
}

// =====================================================================
// 9) tiny 256-col GEMV (Wpl_proj): 512x256
// =====================================================================
__global__ __launch_bounds__(256, 1)
void gemv256_nt(const float* __restrict__ Wm, const float* __restrict__ x,
                float* __restrict__ y) {
    int lane = threadIdx.x & 63, wid = threadIdx.x >> 6;
    int row = blockIdx.x * 4 + wid;
    f32x4 x0 = ld4(x + lane * 4);
    f32x4 w0 = ntld(Wm + (size_t)row * PLD + lane * 4);
    float acc = dot4(w0, x0, 0.f);
    acc = wave_sum(acc);
    if (lane == 0) y[row] = acc;
}

// =====================================================================
// 10) final_fused: out = (x2 + rmsnorm(g2)*(1+w)) * scal. 8x256.
// =====================================================================
__global__ __launch_bounds__(256, 1)
void final_fused(const float* __restrict__ x2, const float* __restrict__ g2,
                 const float* __restrict__ w, const float* __restrict__ scal,
                 float* __restrict__ out) {
    int lane = threadIdx.x & 63;
    f32x4 g4[8];
    #pragma unroll
    for (int c = 0; c < 8; c++) g4[c] = ld4(g2 + c * 256 + lane * 4);
    float ss = 0.f;
    #pragma unroll
    for (int c = 0; c < 8; c++) ss = dot4(g4[c], g4[c], ss);
    ss = wave_sum(ss);
    float rs = rsqrtf(ss / (float)D + EPS);
    int idx = blockIdx.x * 256 + threadIdx.x;
    out[idx] = (x2[idx] + g2[idx] * rs * (1.f + w[idx])) * scal[0];
}

extern "C" void kernel_launch(void* const* d_in, const int* in_sizes, int n_in,
                              void* d_out, int out_size, void* d_ws, size_t ws_size,
                              hipStream_t stream) {
    const float* x_in        = (const float*)d_in[0];
    const float* cosv        = (const float*)d_in[1];
    const float* sinv        = (const float*)d_in[2];
    const float* mask        = (const float*)d_in[3];
    const float* kvc         = (const float*)d_in[4];
    const float* per_layer   = (const float*)d_in[5];
    const float* ln_in_w     = (const float*)d_in[6];
    const float* Wq          = (const float*)d_in[7];
    const float* q_norm_w    = (const float*)d_in[8];
    const float* Wk          = (const float*)d_in[9];
    const float* Wv          = (const float*)d_in[10];
    const float* k_norm_w    = (const float*)d_in[11];
    const float* Wo          = (const float*)d_in[12];
    const float* post_attn_w = (const float*)d_in[13];
    const float* pre_ffn_w   = (const float*)d_in[14];
    const float* Wgate       = (const float*)d_in[15];
    const float* Wup         = (const float*)d_in[16];
    const float* Wdown       = (const float*)d_in[17];
    const float* post_ffn_w  = (const float*)d_in[18];
    const float* Wpl_gate    = (const float*)d_in[19];
    const float* Wpl_proj    = (const float*)d_in[20];
    const float* post_pl_w   = (const float*)d_in[21];
    const float* layer_scal  = (const float*)d_in[22];
    const int*   ring_pos    = (const int*)d_in[23];
    float* out = (float*)d_out;
    float* ws  = (float*)d_ws;

    float* qraw   = ws;          // 2048
    float* kraw   = ws + 2048;   // 512
    float* vraw   = ws + 2560;   // 512
    float* scores = ws + 3072;   // 8*512
    float* attn_o = ws + 7168;   // 2048
    float* y_wo   = ws + 9216;   // 2048
    float* x1     = ws + 11264;  // 2048
    float* act    = ws + 13312;  // 8192
    float* y2     = ws + 21504;  // 2048
    float* x2     = ws + 23552;  // 2048
    float* g      = ws + 25600;  // 256
    float* g2     = ws + 25856;  // 2048

    qkv_fused<<<768, 256, 0, stream>>>(Wq, Wk, Wv, x_in, ln_in_w, qraw, kraw, vraw);
    attn_scores_f<<<64, 256, 0, stream>>>(kvc, qraw, kraw, q_norm_w, k_norm_w,
                                          cosv, sinv, mask, ring_pos, scores);
    attn_softmax<<<8, 256, 0, stream>>>(scores, attn_o);
    attn_pv<<<64, 256, 0, stream>>>(kvc, vraw, scores, ring_pos, attn_o);
    gemv2048_nt<<<512, 256, 0, stream>>>(Wo, attn_o, y_wo);
    gateup_fused<<<2048, 256, 0, stream>>>(Wgate, Wup, x_in, y_wo,
                                           post_attn_w, pre_ffn_w, act, x1);
    down_nt<<<512, 256, 0, stream>>>(Wdown, act, y2);
    plgate_fused<<<64, 256, 0, stream>>>(Wpl_gate, x1, y2, post_ffn_w,
                                         per_layer, g, x2);
    gemv256_nt<<<512, 256, 0, stream>>>(Wpl_proj, g, g2);
    final_fused<<<8, 256, 0, stream>>>(x2, g2, post_pl_w, layer_scal, out);
}